// Round 9
// baseline (387.460 us; speedup 1.0000x reference)
//
#include <hip/hip_runtime.h>
#include <cstdint>
#include <cstddef>

typedef __attribute__((ext_vector_type(4))) float f32x4;
typedef __attribute__((ext_vector_type(8))) short short8;

// ---------- bf16 helpers (bit-level, header-version independent) ----------
__device__ __forceinline__ unsigned short f2bf(float f) {
  unsigned int u = __float_as_uint(f);
  u += 0x7fffu + ((u >> 16) & 1u);            // round to nearest even
  return (unsigned short)(u >> 16);
}
__device__ __forceinline__ float bf2f(unsigned short h) {
  return __uint_as_float(((unsigned int)h) << 16);
}

__device__ __forceinline__ void gload16(const unsigned short* g, unsigned short* l) {
  __builtin_amdgcn_global_load_lds(
      (const __attribute__((address_space(1))) void*)g,
      (__attribute__((address_space(3))) void*)l, 16, 0, 0);
}

// ---------- P1: x f32 -> bf16 ----------
__global__ __launch_bounds__(256) void k_cast(const float* __restrict__ src,
                                              unsigned short* __restrict__ hi) {
  size_t i = ((size_t)blockIdx.x * 256 + threadIdx.x) * 4;
  float4 v = *(const float4*)(src + i);
  *(ushort4*)(hi + i) = make_ushort4(f2bf(v.x), f2bf(v.y), f2bf(v.z), f2bf(v.w));
}

// ---------- P2/P3: transpose f32 [R][C] -> bf16 [C][R] ----------
__global__ __launch_bounds__(256) void k_transpose(const float* __restrict__ src,
                                                   unsigned short* __restrict__ hi,
                                                   int R, int C) {
  __shared__ float tile[32][33];
  int tx = threadIdx.x & 31, ty = threadIdx.x >> 5;  // ty 0..7
  int c0 = blockIdx.x * 32, r0 = blockIdx.y * 32;
#pragma unroll
  for (int i = 0; i < 4; ++i)
    tile[ty + 8 * i][tx] = src[(size_t)(r0 + ty + 8 * i) * C + (c0 + tx)];
  __syncthreads();
#pragma unroll
  for (int i = 0; i < 4; ++i) {
    float v = tile[tx][ty + 8 * i];
    hi[(size_t)(c0 + ty + 8 * i) * R + (r0 + tx)] = f2bf(v);
  }
}

// ---------- GEMM: A[M][K] (bf16, k-contig), B[N][K] (bf16, k-contig) -> C[M][N]
// 256x256 tile, BK=32, 8 waves (2M x 4N, wave-tile 128x64), 4-buffer LDS ring
// (4 x 32KB = 128KB), prefetch distance 3 K-tiles.
// Per K-tile: ONE counted vmcnt + ONE raw s_barrier, then:
//   - issue ALL 12 ds_read_b128 (B0-3 first, then A0-7)
//   - issue all 4 global_load_lds for tile u+3
//   - 32 MFMA ordered mb-outer: MFMA(mb,nb) needs reads {nb+1, 4+mb+1} ->
//     first MFMA unlocked after 5 reads, each next a-read unlocks 4 MFMAs.
//     Compiler emits fine-grained lgkmcnt(N) per dependency (m97 evidence) ->
//     LDS drain overlaps MFMA issue (R8 ran them serially: MfmaUtil 44% ==
//     1242 MFMA cyc / (1242+768 LDS+256 stage+150 sync) serial sum).
// Pipeline correctness (unchanged from R8):
//  - per-wave issue order strictly tile-ordered (4 gloads/tile); at tile u's
//    wait, in-flight <= tiles u,u+1,u+2 = 12 loads; vmcnt(8) -> tile u landed
//    (m135 oldest-first). Tail: rem==1 -> vmcnt(4), rem==0 -> vmcnt(0).
//  - wait BEFORE barrier => collective completeness of buffer u&3.
//  - writes of tile u+3 (buf (u-1)&3) issued after ph(u) barrier => all waves
//    already consumed tile u-1 (their lgkm waits precede barrier arrival).
// LDS swizzle (verified, conflicts=0): row of 32 k = 4 slots of 8 shorts;
// phys slot p at row r holds global k-chunk p ^ ((r>>1)&3); linear LDS dest +
// pre-swizzled global k on stage; fragment reads apply same XOR; A/B share the
// lane->k-chunk convention (contraction safe independent of HW k-labeling).
template<bool BF16OUT>
__global__ __launch_bounds__(512, 2) void k_gemm(const unsigned short* __restrict__ A,
                                                 const unsigned short* __restrict__ B,
                                                 void* __restrict__ Cv, int M, int N, int K) {
  __shared__ unsigned short lds[65536];      // 4 bufs x 16384 shorts = 128 KB
  const int tid = threadIdx.x, wave = tid >> 6, lane = tid & 63;
  const size_t row0 = (size_t)blockIdx.x * 256;
  const size_t col0 = (size_t)blockIdx.y * 256;
  const int wr = wave >> 2, wc = wave & 3;   // 2M x 4N waves
  const int r16 = lane & 15;
  const int ksw = (lane >> 4) ^ ((r16 >> 1) & 3);       // swizzled k-slot (0..3)
  const int aoff = (wr * 128 + r16) * 32 + ksw * 8;     // A region: shorts 0..8191
  const int boff = 8192 + (wc * 64 + r16) * 32 + ksw * 8;
  const int gchunk = (tid & 3) ^ ((tid >> 3) & 3);      // pre-swizzled global k-chunk

  f32x4 acc[8][4];
#pragma unroll
  for (int i = 0; i < 8; ++i)
#pragma unroll
    for (int j = 0; j < 4; ++j) acc[i][j] = (f32x4){0.f, 0.f, 0.f, 0.f};

  // stage one 8KB region (arr 0=A,1=B; inst 0=rows 0-127,1=rows 128-255) of
  // K-tile kt into ring buffer b. Thread: row inst*128+(tid>>2), 16B at slot tid&3.
  auto SREG = [&](int b, int arr, int inst, int kt) {
    const unsigned short* src = arr ? B : A;
    size_t grow = (arr ? col0 : row0) + (size_t)(inst * 128 + (tid >> 2));
    gload16(src + grow * (size_t)K + (size_t)(kt * 32 + gchunk * 8),
            &lds[(b << 14) + arr * 8192 + inst * 4096 + wave * 512]);
  };

  // prologue: stage tiles 0,1,2 into bufs 0,1,2
#pragma unroll
  for (int t = 0; t < 3; ++t) {
    SREG(t, 0, 0, t); SREG(t, 0, 1, t);
    SREG(t, 1, 0, t); SREG(t, 1, 1, t);
  }

  const int nT = K >> 5;
  for (int u = 0; u < nT; ++u) {
    const unsigned short* buf = &lds[(u & 3) << 14];
    const int sb = (u + 3) & 3;
    const bool pf = (u + 3 < nT);
    const int rem = nT - 1 - u;
    if (rem >= 2)      asm volatile("s_waitcnt vmcnt(8)" ::: "memory");
    else if (rem == 1) asm volatile("s_waitcnt vmcnt(4)" ::: "memory");
    else               asm volatile("s_waitcnt vmcnt(0)" ::: "memory");
    asm volatile("s_barrier" ::: "memory");
    // issue ALL fragment reads up front (B first: every MFMA column needs them)
    short8 b4[4], a8[8];
#pragma unroll
    for (int nb = 0; nb < 4; ++nb)
      b4[nb] = *(const short8*)&buf[boff + nb * 512];
#pragma unroll
    for (int mb = 0; mb < 8; ++mb)
      a8[mb] = *(const short8*)&buf[aoff + mb * 512];
    // staging for tile u+3 (vm queue, independent of lgkm queue)
    if (pf) {
      SREG(sb, 0, 0, u + 3); SREG(sb, 0, 1, u + 3);
      SREG(sb, 1, 0, u + 3); SREG(sb, 1, 1, u + 3);
    }
    // 32 MFMAs, mb-outer: consumes a8 in read order -> fine-grained lgkm
    // waits let MFMA overlap the remaining LDS drain.
    __builtin_amdgcn_s_setprio(1);
#pragma unroll
    for (int mb = 0; mb < 8; ++mb)
#pragma unroll
      for (int nb = 0; nb < 4; ++nb)
        acc[mb][nb] = __builtin_amdgcn_mfma_f32_16x16x32_bf16(a8[mb], b4[nb], acc[mb][nb], 0, 0, 0);
    __builtin_amdgcn_s_setprio(0);
  }

  // C/D layout (HW-verified): col = lane&15, row = (lane>>4)*4 + reg
#pragma unroll
  for (int m = 0; m < 8; ++m)
#pragma unroll
    for (int n = 0; n < 4; ++n) {
      size_t row = row0 + wr * 128 + m * 16 + (lane >> 4) * 4;
      size_t col = col0 + wc * 64 + n * 16 + r16;
      if (BF16OUT) {
        unsigned short* C = (unsigned short*)Cv;
#pragma unroll
        for (int r = 0; r < 4; ++r) C[(row + r) * (size_t)N + col] = f2bf(acc[m][n][r]);
      } else {
        float* C = (float*)Cv;
#pragma unroll
        for (int r = 0; r < 4; ++r) C[(row + r) * (size_t)N + col] = acc[m][n][r];
      }
    }
}

// ---------- scan constants ----------
#define SB 4
#define ST 4096
#define SE 2048
#define CHUNK 64
#define NCHUNK 64
#define NCHAIN (SB * SE)  // 8192

// transforms via native v_exp_f32/v_log_f32 (__expf/__logf), ~1e-7 abs error in
// log-space (irrelevant vs 0.134 budget). proj is bf16 (window-bounded log-space
// error ~0.01-0.03; measured absmax unchanged at 0.03125).
__device__ __forceinline__ void transform(float k, float hx, float& lc, float& lv) {
  float u = __expf(-fabsf(k));
  float sp = fmaxf(k, 0.f) + __logf(1.f + u);   // softplus(k)
  lc = -sp;                                     // log(1 - sigmoid(k))
  float eh = __expf(fminf(hx, 0.f));            // exp(hx) for hx<0 (clamped: no overflow)
  float arg = (hx >= 0.f) ? (hx + 0.5f) : (1.f + eh);
  float vl = __logf(arg);
  float lg = (hx >= 0.f) ? vl : (hx - vl);      // log g(hx)
  lv = lg + k + lc;                             // log g + log sigmoid(k)
}
__device__ __forceinline__ float lse_step(float lc, float lv, float S) {
  float a1 = lc + S;
  float m = fmaxf(a1, lv);
  float d = fminf(a1, lv) - m;                  // <= 0 (or -inf)
  return m + __logf(1.f + __expf(d));
}

// K2: transforms + chunk-local scan (from -inf) -> chunk summaries ONLY.
__global__ __launch_bounds__(256) void k_scan1(const unsigned short* __restrict__ proj,
                                               const float* __restrict__ bfv,
                                               float* __restrict__ Ac,
                                               float* __restrict__ Bc) {
  int idx = blockIdx.x * 256 + threadIdx.x;  // (c, b, e) with e fastest
  int e = idx & (SE - 1), b = (idx >> 11) & 3, c = idx >> 13;
  const float bk = bfv[e], bh = bfv[SE + e];
  float A = 0.f, S = -INFINITY;
  size_t base = ((size_t)(b * ST + c * CHUNK) * (2 * SE)) + e;
  for (int i = 0; i < CHUNK; ++i) {
    float lc, lv;
    transform(bf2f(proj[base]) + bk, bf2f(proj[base + SE]) + bh, lc, lv);
    A += lc;
    S = lse_step(lc, lv, S);
    base += 2 * SE;
  }
  int chain = b * SE + e;
  Ac[(size_t)c * NCHAIN + chain] = A;
  Bc[(size_t)c * NCHAIN + chain] = S;
}

// K3: scan over chunk summaries -> incoming state per chunk
__global__ __launch_bounds__(256) void k_scan2(const float* __restrict__ lh0,
                                               const float* __restrict__ Ac,
                                               const float* __restrict__ Bc,
                                               float* __restrict__ Hin) {
  int chain = blockIdx.x * 256 + threadIdx.x;  // 8192 = b*E + e
  float H = lh0[chain];
  for (int c = 0; c < NCHUNK; ++c) {
    Hin[(size_t)c * NCHAIN + chain] = H;
    float a = Ac[(size_t)c * NCHAIN + chain] + H;
    float bv = Bc[(size_t)c * NCHAIN + chain];
    float m = fmaxf(a, bv);
    float d = fminf(a, bv) - m;
    H = m + __logf(1.f + __expf(d));
  }
}

// K4: replay scan (recomputing lv/lc from bf16 proj) with true incoming state;
// emit h_t (bf16) and out2 slices (f32)
__global__ __launch_bounds__(256) void k_scan3(const unsigned short* __restrict__ proj,
                                               const float* __restrict__ bfv,
                                               const float* __restrict__ Hin,
                                               unsigned short* __restrict__ ht,
                                               float* __restrict__ out2) {
  int idx = blockIdx.x * 256 + threadIdx.x;
  int e = idx & (SE - 1), b = (idx >> 11) & 3, c = idx >> 13;
  const float bk = bfv[e], bh = bfv[SE + e];
  float S = Hin[(size_t)c * NCHAIN + b * SE + e];
  size_t base = ((size_t)(b * ST + c * CHUNK) * (2 * SE)) + e;
  int t = c * CHUNK;
  size_t hto = ((size_t)(b * ST + t) * SE) + e;
  for (int i = 0; i < CHUNK; ++i, ++t) {
    float lc, lv;
    transform(bf2f(proj[base]) + bk, bf2f(proj[base + SE]) + bh, lc, lv);
    S = lse_step(lc, lv, S);
    ht[hto] = f2bf(__expf(S));
    if (t >= 2 && ((t - 2) % 3) == 0) {   // t in {2,5,...,4094}
      int j = (t - 2) / 3;
      out2[((size_t)b * 1365 + j) * SE + e] = S;
    }
    base += 2 * SE;
    hto += SE;
  }
}

// ---------- launch ----------
extern "C" void kernel_launch(void* const* d_in, const int* in_sizes, int n_in,
                              void* d_out, int out_size, void* d_ws, size_t ws_size,
                              hipStream_t stream) {
  const float* x   = (const float*)d_in[0];
  const float* lh0 = (const float*)d_in[1];
  const float* wf  = (const float*)d_in[2];
  const float* bfv = (const float*)d_in[3];
  const float* wd  = (const float*)d_in[4];
  float* out1 = (float*)d_out;
  float* out2 = out1 + (size_t)SB * ST * 1024;

  char* p = (char*)d_ws;
  unsigned short* proj = (unsigned short*)p; p += 16384ull * 4096 * 2;  // 134 MB bf16
  unsigned short* xhi  = (unsigned short*)p; p += 16384ull * 1024 * 2;
  unsigned short* wfh  = (unsigned short*)p; p += 4096ull * 1024 * 2;
  unsigned short* wdt  = (unsigned short*)p; p += 1024ull * 2048 * 2;
  unsigned short* ht   = (unsigned short*)p; p += 16384ull * 2048 * 2;  // 67 MB
  float* Ac            = (float*)p;          p += 64ull * 8192 * 4;
  float* Bc            = (float*)p;          p += 64ull * 8192 * 4;
  float* Hin           = (float*)p;          p += 64ull * 8192 * 4;

  // pre-passes
  hipLaunchKernelGGL(k_cast, dim3(16384), dim3(256), 0, stream, x, xhi);
  hipLaunchKernelGGL(k_transpose, dim3(128, 32), dim3(256), 0, stream, wf, wfh, 1024, 4096);
  hipLaunchKernelGGL(k_transpose, dim3(32, 64),  dim3(256), 0, stream, wd, wdt, 2048, 1024);
  // GEMM1 (bf16 in/out): proj = x @ w_f
  hipLaunchKernelGGL((k_gemm<true>), dim3(64, 16), dim3(512), 0, stream,
                     xhi, wfh, (void*)proj, 16384, 4096, 1024);
  // 3-pass chunked log-space scan (proj bf16, read-only; scan3 recomputes)
  hipLaunchKernelGGL(k_scan1, dim3(2048), dim3(256), 0, stream, proj, bfv, Ac, Bc);
  hipLaunchKernelGGL(k_scan2, dim3(32), dim3(256), 0, stream, lh0, Ac, Bc, Hin);
  hipLaunchKernelGGL(k_scan3, dim3(2048), dim3(256), 0, stream, proj, bfv, Hin, ht, out2);
  // GEMM2 (bf16 in, f32 out): out1 = h_t @ w_down
  hipLaunchKernelGGL((k_gemm<false>), dim3(64, 4), dim3(512), 0, stream,
                     ht, wdt, (void*)out1, 16384, 1024, 2048);
}